// Round 10
// baseline (284.926 us; speedup 1.0000x reference)
//
#include <hip/hip_runtime.h>

// LIF spiking layer forward: x (B,C,T) fp32 -> spikes (B,C,T) fp32.
// Recurrence per row r=(b,c):
//   rst   = spk_{t-1} * Vth[c]
//   mem_t = (mem_{t-1} - rst)*beta + x_t*alpha
//   spk_t = (mem_t - Vth[c] > 0) ? 1 : 0
// Bit-exact vs numpy: no FMA contraction; rst via select (1.0*Vth == Vth,
// mem - 0.0 == mem).
//
// R1: occupancy structurally 1 wave/CU (16384 rows = 256 waves).
// R2: nt stores -> 3.5x write amplification. Reverted.
// R3: asm-VGPR loads, counted vmcnt, no LDS: 97.6 us, bit-exact.
// R4: asm stores consuming compiler ds_reads -> garbage. Never again.
// R5/R7: asm-VGPR loads + LDS -> abort: allocator can move/spill an asm
//     load's dest before the hardware write lands. Asm VGPR loads are
//     unusable under pressure.
// R6: pure-C++ LDS transpose: 89 us. Compiler exposes ~1 full load latency
//     per tile (VGPR=56) -> implies L_eff ~2500-3000 cyc under traffic.
// R8: glds 3-buffer, dist-2: PASSED 100 us. Pipeline held but slower than
//     R6. Diagnosis: (a) WAITV(16) was wrong for D=3 (correct 24): forced
//     S(t-2) retirement every body; (b) distance 2 << L_eff/compute ratio
//     (Little's law on observed 2 TB/s @ ~6MB in flight -> L_eff ~3 us).
// R9: D=5 buffers (4-deep prefetch), waits retire EXACTLY through L(t):
//     stores issued BEFORE each body's glds, region order pinned by a
//     zero-cost compiler fence + sched_barrier, N=48 steady (56 peak
//     outstanding <= 63). Compute/transpose/store path identical to R6/R8.
//     (R9 bench run died in infra -- "container failed twice" -- this is an
//     unchanged resubmit.)

constexpr int T_LEN = 2000;
constexpr int CH    = 32;                      // timesteps per full tile
constexpr int NQ    = CH / 4;                  // 8 glds instrs per tile
constexpr int NFULL = 62;                      // 62*32 = 1984
constexpr int TAILQ = (T_LEN - NFULL * CH)/4;  // 4 quads = 16 steps
constexpr int LDSW  = 33;                      // transpose row stride (dwords)
constexpr int XBUF  = NQ * 256;                // dwords per x-buffer (8 KB)
constexpr int NBUF  = 5;                       // x-buffers (4-deep prefetch)

typedef float nfloat4 __attribute__((ext_vector_type(4)));

// Counted wait; "memory" fences all compiler memory ops and glds across it;
// sched_barrier stops hoisting of register-only consumers (rule #18).
#define WAITV(N) do { \
    asm volatile("s_waitcnt vmcnt(" #N ")" ::: "memory"); \
    __builtin_amdgcn_sched_barrier(0); } while (0)

// Zero-instruction fence: pins VMEM issue order (stores vs glds) at both IR
// and MIR level so the vmcnt region totals are exact.
#define VMFENCE() do { \
    asm volatile("" ::: "memory"); \
    __builtin_amdgcn_sched_barrier(0); } while (0)

// Direct global->LDS: lane L's 16B land at (wave-uniform lp) + L*16.
// No VGPR destination -> nothing for the allocator to spill (R5/R7 fix).
__device__ __forceinline__ void glds16(const float* gp, float* lp) {
    __builtin_amdgcn_global_load_lds(
        (const __attribute__((address_space(1))) void*)gp,
        (__attribute__((address_space(3))) void*)lp, 16, 0, 0);
}

// Issue N glds for one tile: instr q covers timesteps q*4..q*4+3 of every
// lane's row; lands at xb[q*256 + lane*4 + j].
template <int N>
__device__ __forceinline__ void load_tile(const float* xlt, float* xb) {
#pragma unroll
    for (int q = 0; q < N; ++q) glds16(xlt + q * 4, xb + q * 256);
}

__device__ __forceinline__ float lif_step(float xval, float alpha, float beta, float vth,
                                          float& mem, float& vdiff, bool& spk) {
#pragma clang fp contract(off)
    float xa = xval * alpha;             // x_t * alpha (separate mul, like np)
    // Speculative both-branch update; bit-exact vs (mem - rst)*beta + xa:
    //   spk==1: rst = 1.0*Vth = Vth, mem-Vth == vdiff (from last step)
    //   spk==0: rst = 0.0*Vth = 0.0, mem-0.0 == mem
    float p0 = mem   * beta;
    float p1 = vdiff * beta;
    float q0 = p0 + xa;
    float q1 = p1 + xa;
    mem   = spk ? q1 : q0;
    vdiff = mem - vth;
    spk   = vdiff > 0.0f;
    return spk ? 1.0f : 0.0f;
}

// Plain ds_read of this lane's N quads from an x-buffer (lgkmcnt managed by
// the compiler; ordered vs glds by the preceding WAITV).
template <int N>
__device__ __forceinline__ void read_x(nfloat4 (&xv)[NQ], const float* xrd) {
#pragma unroll
    for (int q = 0; q < N; ++q)
        xv[q] = *reinterpret_cast<const nfloat4*>(xrd + q * 256);
}

// lif over N quads; spikes into this lane's transpose row (stride-33:
// worst 2-way banking = free). Single wave: DS ops in order, no barrier.
template <int N>
__device__ __forceinline__ void lif_tile(const nfloat4 (&xv)[NQ], float* shrow,
                                         float alpha, float beta, float vth,
                                         float& mem, float& vdiff, bool& spk) {
#pragma clang fp contract(off)
#pragma unroll
    for (int q = 0; q < N; ++q) {
        shrow[q*4 + 0] = lif_step(xv[q].x, alpha, beta, vth, mem, vdiff, spk);
        shrow[q*4 + 1] = lif_step(xv[q].y, alpha, beta, vth, mem, vdiff, spk);
        shrow[q*4 + 2] = lif_step(xv[q].z, alpha, beta, vth, mem, vdiff, spk);
        shrow[q*4 + 3] = lif_step(xv[q].w, alpha, beta, vth, mem, vdiff, spk);
    }
}

// Transposed coalesced store (R6-proven): instr k writes rows sub+8k
// (sub=0..7), each 128B contiguous. Exactly 8 vmem stores (8000B-strided
// rows cannot merge) -> region totals exact.
__device__ __forceinline__ void store_tile(const float* __restrict__ sh, int sub, int off,
                                           float* __restrict__ op) {
#pragma unroll
    for (int k = 0; k < 8; ++k) {
        const float* p = sh + (sub + 8*k) * LDSW + off * 4;
        float4 s = make_float4(p[0], p[1], p[2], p[3]);
        *reinterpret_cast<float4*>(op + (size_t)(8*k) * T_LEN) = s;
    }
}

__global__ __launch_bounds__(64) void lif_fwd_kernel(const float* __restrict__ x,
                                                     const float* __restrict__ alpha_p,
                                                     const float* __restrict__ beta_p,
                                                     const float* __restrict__ vth_p,
                                                     float* __restrict__ out,
                                                     int C, int rows) {
#pragma clang fp contract(off)
    // Requires rows % 64 == 0 (true: B*C = 16384).
    __shared__ float shx[NBUF * XBUF];              // 40960 B: 5 x-buffers
    __shared__ float sh[64 * LDSW];                 // 8448 B: spike transpose

    const int lane = threadIdx.x;
    const int row0 = blockIdx.x * 64;
    const int row  = row0 + lane;
    if (row >= rows) return;

    const float alpha = alpha_p[0];
    const float beta  = beta_p[0];
    const float vth   = vth_p[(unsigned)row % (unsigned)C];
    // Materialize (and vmcnt-drain) all scalar/VMEM arg loads HERE so manual
    // vmcnt counting starts from zero outstanding. (R3/R8-proven.)
    asm volatile("" :: "v"(alpha), "v"(beta), "v"(vth));

    const float* xl  = x + (size_t)row * T_LEN;     // per-lane global base
    const float* xrd = shx + lane * 4;              // per-lane LDS read base
    float* __restrict__ shrow = sh + lane * LDSW;   // transpose write row
    const int sub = lane >> 3;                      // 0..7: row-in-group
    const int off = lane & 7;                       // 0..7: 16B column
    float* __restrict__ outp = out + (size_t)(row0 + sub) * T_LEN + off * 4;

    float mem = 0.0f, vdiff = 0.0f;
    bool  spk = false;                              // vdiff only read when spk
    nfloat4 xv[NQ];

    // ---- vmcnt ledger (issue order pinned by VMFENCE; in-order retire) ----
    // Stream: L0 L1 L2 L3 | body t: [S(t) ; L(t+4)] ...
    // Body t wait must retire through L(t); allowed outstanding after L(t):
    //   t=0: L1..L3            = 24
    //   t=1: L2,L3,S0,L4       = 32
    //   t=2: L3,S0,L4,S1,L5    = 40
    //   t>=3: 3 x [S,L] pairs  = 48
    //   t=59: [S56,L60][S57,L61][S58,Lt4] = 44
    //   t=60: [S57,L61][S58,Lt4][S59]     = 36
    //   t=61: [S58,Lt4][S59][S60]         = 28
    //   tail: S59,S60,S61                 = 24
    // Peak outstanding 56 <= 63.
    load_tile<NQ>(xl + 0*CH, shx + 0*XBUF); VMFENCE();
    load_tile<NQ>(xl + 1*CH, shx + 1*XBUF); VMFENCE();
    load_tile<NQ>(xl + 2*CH, shx + 2*XBUF); VMFENCE();
    load_tile<NQ>(xl + 3*CH, shx + 3*XBUF);

#define BODY_FULL(T, N, RBUF, LBUF)                                          \
    do {                                                                     \
        WAITV(N);                                                            \
        read_x<NQ>(xv, xrd + (RBUF) * XBUF);                                 \
        lif_tile<NQ>(xv, shrow, alpha, beta, vth, mem, vdiff, spk);          \
        store_tile(sh, sub, off, outp + (size_t)(T) * CH);                   \
        VMFENCE();                                                           \
        load_tile<NQ>(xl + (size_t)((T) + 4) * CH, shx + (LBUF) * XBUF);     \
    } while (0)

#define BODY_NOLOAD(T, N, RBUF)                                              \
    do {                                                                     \
        WAITV(N);                                                            \
        read_x<NQ>(xv, xrd + (RBUF) * XBUF);                                 \
        lif_tile<NQ>(xv, shrow, alpha, beta, vth, mem, vdiff, spk);          \
        store_tile(sh, sub, off, outp + (size_t)(T) * CH);                   \
    } while (0)

    // Ramp t=0..3 (buffers t%5; prefetch into (t+4)%5).
    BODY_FULL(0, 24, 0, 4);
    BODY_FULL(1, 32, 1, 0);
    BODY_FULL(2, 40, 2, 1);
    BODY_FULL(3, 48, 3, 2);

    // Steady t=4..57.
    int par = 4;                                    // t % 5
    for (int t = 4; t <= 57; ++t) {
        WAITV(48);
        read_x<NQ>(xv, xrd + par * XBUF);
        lif_tile<NQ>(xv, shrow, alpha, beta, vth, mem, vdiff, spk);
        store_tile(sh, sub, off, outp + (size_t)t * CH);
        VMFENCE();
        int par2 = par + 4; if (par2 >= NBUF) par2 -= NBUF;  // (t+4)%5
        load_tile<NQ>(xl + (size_t)(t + 4) * CH, shx + par2 * XBUF);
        if (++par == NBUF) par = 0;
    }
    // t=58 (buf 3): last full-tile prefetch is the 16-step tail -> buf 2.
    WAITV(48);
    read_x<NQ>(xv, xrd + 3 * XBUF);
    lif_tile<NQ>(xv, shrow, alpha, beta, vth, mem, vdiff, spk);
    store_tile(sh, sub, off, outp + (size_t)58 * CH);
    VMFENCE();
    load_tile<TAILQ>(xl + (size_t)NFULL * CH, shx + 2 * XBUF);

    BODY_NOLOAD(59, 44, 4);
    BODY_NOLOAD(60, 36, 0);
    BODY_NOLOAD(61, 28, 1);

    // Tail (16 steps), buf 2.
    WAITV(24);
    read_x<TAILQ>(xv, xrd + 2 * XBUF);
    lif_tile<TAILQ>(xv, shrow, alpha, beta, vth, mem, vdiff, spk);
    {   // tail store: 64B/row, 4 lanes/row, 16 rows/instr, 4 instrs (R6 code)
        const int subt = lane >> 2;                 // 0..15
        const int offt = lane & 3;                  // 0..3
        float* opt = out + (size_t)(row0 + subt) * T_LEN + NFULL * CH + offt * 4;
#pragma unroll
        for (int k = 0; k < 4; ++k) {
            const float* p = sh + (subt + 16*k) * LDSW + offt * 4;
            float4 s = make_float4(p[0], p[1], p[2], p[3]);
            *reinterpret_cast<float4*>(opt + (size_t)(16*k) * T_LEN) = s;
        }
    }
#undef BODY_FULL
#undef BODY_NOLOAD
}

extern "C" void kernel_launch(void* const* d_in, const int* in_sizes, int n_in,
                              void* d_out, int out_size, void* d_ws, size_t ws_size,
                              hipStream_t stream) {
    const float* x     = (const float*)d_in[0];
    const float* alpha = (const float*)d_in[1];
    const float* beta  = (const float*)d_in[2];
    const float* vth   = (const float*)d_in[3];
    float* out = (float*)d_out;

    const int C    = in_sizes[3];            // 256
    const int rows = in_sizes[0] / T_LEN;    // B*C = 16384

    dim3 grid((rows + 63) / 64), block(64);
    lif_fwd_kernel<<<grid, block, 0, stream>>>(x, alpha, beta, vth, out, C, rows);
}